// Round 2
// baseline (688.662 us; speedup 1.0000x reference)
//
#include <hip/hip_runtime.h>
#include <math.h>

#define Hd 128
#define Rr 3
#define Ll 4
#define NPW 32   // nodes per wave

typedef float f32x4 __attribute__((ext_vector_type(4)));
typedef short s16x8 __attribute__((ext_vector_type(8)));

__device__ __forceinline__ unsigned short f2bf(float f){
    unsigned u = __float_as_uint(f);
    return (unsigned short)((u + 0x7FFFu + ((u >> 16) & 1u)) >> 16);
}
__device__ __forceinline__ float bf2f(unsigned short h){
    return __uint_as_float(((unsigned)h) << 16);
}
__device__ __forceinline__ void split8(float4 a, float4 b, s16x8& hi, s16x8& lo){
    float v[8] = {a.x, a.y, a.z, a.w, b.x, b.y, b.z, b.w};
    #pragma unroll
    for (int j = 0; j < 8; ++j){
        unsigned short h = f2bf(v[j]);
        hi[j] = (short)h;
        lo[j] = (short)f2bf(v[j] - bf2f(h));
    }
}
__device__ __forceinline__ int lower_bound_i32(const int* __restrict__ a, int n, int key){
    int lo = 0, hi = n;
    while (lo < hi){
        int mid = (lo + hi) >> 1;
        if (a[mid] < key) lo = mid + 1; else hi = mid;
    }
    return lo;
}

// ---- McT = fold(out_w, wv), bc = fold(out_w, bv) + out_b  (same as round 1, verified) ----
__global__ void fold_proj_kernel(const float* __restrict__ in_proj_w,
                                 const float* __restrict__ in_proj_b,
                                 const float* __restrict__ out_w,
                                 const float* __restrict__ out_b,
                                 float* __restrict__ McT,
                                 float* __restrict__ bc)
{
    const int i = blockIdx.x;   // 0..127 (k index)
    const int j = threadIdx.x;  // 0..127 (n index)
    float acc = 0.f;
    for (int k = 0; k < Hd; ++k)
        acc = fmaf(out_w[j * Hd + k], in_proj_w[(2 * Hd + k) * Hd + i], acc);
    McT[i * Hd + j] = acc;
    if (i == 0){
        float b = out_b[j];
        for (int k = 0; k < Hd; ++k)
            b = fmaf(out_w[j * Hd + k], in_proj_b[2 * Hd + k], b);
        bc[j] = b;
    }
}

// ---- split weights into bf16 hi/lo, pre-swizzled into MFMA B-fragment order ----
// frag elem j of lane l at (mat,kc,nc):  W[kc*32 + (l>>4)*8 + j][nc*16 + (l&15)]
__global__ void pack_kernel(const float* __restrict__ r_whh, const float* __restrict__ u_whh,
                            const float* __restrict__ r_wxh, const float* __restrict__ u_wxh,
                            const float* __restrict__ c_whh, const float* __restrict__ c_wxh,
                            const float* __restrict__ McT,
                            unsigned short* __restrict__ whi, unsigned short* __restrict__ wlo)
{
    const int mat  = blockIdx.y;   // 0..6
    const int tile = blockIdx.x;   // 0..31 : kc = tile>>3, nc = tile&7
    const int l    = threadIdx.x;  // 0..63
    const float* W;
    switch (mat){
        case 0: W = r_whh; break;  case 1: W = u_whh; break;
        case 2: W = r_wxh; break;  case 3: W = u_wxh; break;
        case 4: W = c_whh; break;  case 5: W = c_wxh; break;
        default: W = McT;
    }
    const int kc = tile >> 3, nc = tile & 7;
    const int kbase = kc * 32 + (l >> 4) * 8;
    const int n = nc * 16 + (l & 15);
    const size_t obase = ((size_t)(mat * 32 + tile) * 64 + l) * 8;
    #pragma unroll
    for (int j = 0; j < 8; ++j){
        float v = W[(kbase + j) * Hd + n];
        unsigned short h = f2bf(v);
        whi[obase + j] = h;
        wlo[obase + j] = f2bf(v - bf2f(h));
    }
}

#define BFRAG(arr, mat, kc, nc) (*(const s16x8*)((arr) + ((((mat) * 32 + (kc) * 8 + (nc)) * 64 + l) * 8)))

#define MM3(acc, AH, AL, BH, BL)                                              \
    acc = __builtin_amdgcn_mfma_f32_16x16x32_bf16(AH, BH, acc, 0, 0, 0);      \
    acc = __builtin_amdgcn_mfma_f32_16x16x32_bf16(AL, BH, acc, 0, 0, 0);      \
    acc = __builtin_amdgcn_mfma_f32_16x16x32_bf16(AH, BL, acc, 0, 0, 0);

__global__ __launch_bounds__(256, 1) void gru_mfma_kernel(
    const float* __restrict__ x_rank,
    const int* __restrict__ valid_idx, int nv,
    const float* __restrict__ r_b, const float* __restrict__ u_b, const float* __restrict__ c_b,
    const unsigned short* __restrict__ whi, const unsigned short* __restrict__ wlo,
    const float* __restrict__ bc,
    float* __restrict__ out, int N)
{
    __shared__ float hL_all[4][32][132];
    __shared__ float rhL_all[4][32][132];
    __shared__ int lo_all[4][32];
    __shared__ int hi_all[4][32];

    const int tid = threadIdx.x;
    const int wid = tid >> 6;
    const int l   = tid & 63;
    const int lr  = l & 15;
    const int lg  = l >> 4;
    const int n0  = (blockIdx.x * 4 + wid) * NPW;

    float (*hL)[132]  = hL_all[wid];
    float (*rhL)[132] = rhL_all[wid];
    int* loL = lo_all[wid];
    int* hiL = hi_all[wid];

    // zero own h tile (t=0 state)
    {
        float* hz = (float*)hL;
        for (int i = l; i < 32 * 132; i += 64) hz[i] = 0.f;
    }

    // per-nc biases (col = nc*16+lr)
    float rb[8], ub[8], cb[8], ob[8];
    #pragma unroll
    for (int nc = 0; nc < 8; ++nc){
        rb[nc] = r_b[nc * 16 + lr];
        ub[nc] = u_b[nc * 16 + lr];
        cb[nc] = c_b[nc * 16 + lr];
        ob[nc] = bc[nc * 16 + lr];
    }

    s16x8 ahi[2][4], alo[2][4];   // A-frags: h, then r*h, then h'
    s16x8 xhi[2][4], xlo[2][4];
    f32x4 zreg[8][2];

    #pragma unroll 1
    for (int t = 0; t < Rr; ++t){
        // ---- output-row ranges for this t ----
        if (l < 32){
            int n = n0 + l, lo = 0, hi = 0;
            if (n < N){
                int F = (n * Rr + t) * Ll;
                lo = lower_bound_i32(valid_idx, nv, F);
                hi = lower_bound_i32(valid_idx, nv, F + Ll);
            }
            loL[l] = lo; hiL[l] = hi;
        }

        // ---- x A-frags ----
        #pragma unroll
        for (int mt = 0; mt < 2; ++mt){
            int n = n0 + mt * 16 + lr;
            bool ok = n < N;
            const float* xp = x_rank + ((size_t)(ok ? n : 0) * Rr + t) * Hd;
            #pragma unroll
            for (int kc = 0; kc < 4; ++kc){
                float4 a = *(const float4*)(xp + kc * 32 + lg * 8);
                float4 b = *(const float4*)(xp + kc * 32 + lg * 8 + 4);
                if (!ok){ a = make_float4(0.f,0.f,0.f,0.f); b = make_float4(0.f,0.f,0.f,0.f); }
                split8(a, b, xhi[mt][kc], xlo[mt][kc]);
            }
        }

        // ---- h A-frags from LDS ----
        #pragma unroll
        for (int mt = 0; mt < 2; ++mt)
            #pragma unroll
            for (int kc = 0; kc < 4; ++kc){
                const float* p = &hL[mt * 16 + lr][kc * 32 + lg * 8];
                split8(*(const float4*)p, *(const float4*)(p + 4), ahi[mt][kc], alo[mt][kc]);
            }

        // ---- r/z gates ----
        #pragma unroll
        for (int nc = 0; nc < 8; ++nc){
            f32x4 ar0 = {rb[nc], rb[nc], rb[nc], rb[nc]};
            f32x4 ar1 = ar0;
            f32x4 az0 = {ub[nc], ub[nc], ub[nc], ub[nc]};
            f32x4 az1 = az0;
            #pragma unroll
            for (int kc = 0; kc < 4; ++kc){
                s16x8 b0h = BFRAG(whi, 0, kc, nc), b0l = BFRAG(wlo, 0, kc, nc);
                s16x8 b1h = BFRAG(whi, 1, kc, nc), b1l = BFRAG(wlo, 1, kc, nc);
                MM3(ar0, ahi[0][kc], alo[0][kc], b0h, b0l);
                MM3(ar1, ahi[1][kc], alo[1][kc], b0h, b0l);
                MM3(az0, ahi[0][kc], alo[0][kc], b1h, b1l);
                MM3(az1, ahi[1][kc], alo[1][kc], b1h, b1l);
                s16x8 b2h = BFRAG(whi, 2, kc, nc), b2l = BFRAG(wlo, 2, kc, nc);
                s16x8 b3h = BFRAG(whi, 3, kc, nc), b3l = BFRAG(wlo, 3, kc, nc);
                MM3(ar0, xhi[0][kc], xlo[0][kc], b2h, b2l);
                MM3(ar1, xhi[1][kc], xlo[1][kc], b2h, b2l);
                MM3(az0, xhi[0][kc], xlo[0][kc], b3h, b3l);
                MM3(az1, xhi[1][kc], xlo[1][kc], b3h, b3l);
            }
            #pragma unroll
            for (int mt = 0; mt < 2; ++mt){
                f32x4 arr = mt ? ar1 : ar0;
                f32x4 azz = mt ? az1 : az0;
                #pragma unroll
                for (int i = 0; i < 4; ++i){
                    int row = mt * 16 + lg * 4 + i, col = nc * 16 + lr;
                    float r = 1.f / (1.f + __expf(-arr[i]));
                    float z = 1.f / (1.f + __expf(-azz[i]));
                    zreg[nc][mt][i] = z;
                    rhL[row][col] = r * hL[row][col];
                }
            }
        }
        __syncthreads();

        // ---- (r*h) A-frags ----
        #pragma unroll
        for (int mt = 0; mt < 2; ++mt)
            #pragma unroll
            for (int kc = 0; kc < 4; ++kc){
                const float* p = &rhL[mt * 16 + lr][kc * 32 + lg * 8];
                split8(*(const float4*)p, *(const float4*)(p + 4), ahi[mt][kc], alo[mt][kc]);
            }

        // ---- c gate + h update ----
        #pragma unroll
        for (int nc = 0; nc < 8; ++nc){
            f32x4 ac0 = {cb[nc], cb[nc], cb[nc], cb[nc]};
            f32x4 ac1 = ac0;
            #pragma unroll
            for (int kc = 0; kc < 4; ++kc){
                s16x8 b4h = BFRAG(whi, 4, kc, nc), b4l = BFRAG(wlo, 4, kc, nc);
                s16x8 b5h = BFRAG(whi, 5, kc, nc), b5l = BFRAG(wlo, 5, kc, nc);
                MM3(ac0, ahi[0][kc], alo[0][kc], b4h, b4l);
                MM3(ac1, ahi[1][kc], alo[1][kc], b4h, b4l);
                MM3(ac0, xhi[0][kc], xlo[0][kc], b5h, b5l);
                MM3(ac1, xhi[1][kc], xlo[1][kc], b5h, b5l);
            }
            #pragma unroll
            for (int mt = 0; mt < 2; ++mt){
                f32x4 acc = mt ? ac1 : ac0;
                #pragma unroll
                for (int i = 0; i < 4; ++i){
                    int row = mt * 16 + lg * 4 + i, col = nc * 16 + lr;
                    float e = __expf(2.f * acc[i]);
                    float c = 1.f - 2.f / (e + 1.f);   // tanh, saturates correctly
                    float ho = hL[row][col];
                    float z  = zreg[nc][mt][i];
                    hL[row][col] = ho + z * (c - ho);
                }
            }
        }
        __syncthreads();

        // ---- h' A-frags ----
        #pragma unroll
        for (int mt = 0; mt < 2; ++mt)
            #pragma unroll
            for (int kc = 0; kc < 4; ++kc){
                const float* p = &hL[mt * 16 + lr][kc * 32 + lg * 8];
                split8(*(const float4*)p, *(const float4*)(p + 4), ahi[mt][kc], alo[mt][kc]);
            }

        // hoist lo/hi run bounds
        int lor[2][4], hir[2][4];
        #pragma unroll
        for (int mt = 0; mt < 2; ++mt)
            #pragma unroll
            for (int i = 0; i < 4; ++i){
                int row = mt * 16 + lg * 4 + i;
                lor[mt][i] = loL[row];
                hir[mt][i] = hiL[row];
            }

        // ---- fused output projection + scatter ----
        #pragma unroll
        for (int nc = 0; nc < 8; ++nc){
            f32x4 ao0 = {ob[nc], ob[nc], ob[nc], ob[nc]};
            f32x4 ao1 = ao0;
            #pragma unroll
            for (int kc = 0; kc < 4; ++kc){
                s16x8 b6h = BFRAG(whi, 6, kc, nc), b6l = BFRAG(wlo, 6, kc, nc);
                MM3(ao0, ahi[0][kc], alo[0][kc], b6h, b6l);
                MM3(ao1, ahi[1][kc], alo[1][kc], b6h, b6l);
            }
            #pragma unroll
            for (int mt = 0; mt < 2; ++mt){
                f32x4 aoo = mt ? ao1 : ao0;
                #pragma unroll
                for (int i = 0; i < 4; ++i){
                    float v = aoo[i];
                    int col = nc * 16 + lr;
                    for (int rr = lor[mt][i]; rr < hir[mt][i]; ++rr)
                        out[(size_t)rr * Hd + col] = v;
                }
            }
        }
        __syncthreads();
    }
}

__global__ void he_order_kernel(const int* __restrict__ he_order,
                                float* __restrict__ out_tail, int nv)
{
    const int i = blockIdx.x * 256 + threadIdx.x;
    if (i < nv) out_tail[i] = (float)he_order[i];
}

extern "C" void kernel_launch(void* const* d_in, const int* in_sizes, int n_in,
                              void* d_out, int out_size, void* d_ws, size_t ws_size,
                              hipStream_t stream)
{
    const float* x_rank    = (const float*)d_in[0];
    // d_in[1] he_features, d_in[2] he_idx: dead (softmax over singleton axis == 1)
    const int*   valid_idx = (const int*)d_in[3];
    const int*   he_order  = (const int*)d_in[4];
    const float* r_whh = (const float*)d_in[5];
    const float* r_wxh = (const float*)d_in[6];
    const float* r_b   = (const float*)d_in[7];
    const float* u_whh = (const float*)d_in[8];
    const float* u_wxh = (const float*)d_in[9];
    const float* u_b   = (const float*)d_in[10];
    const float* c_whh = (const float*)d_in[11];
    const float* c_wxh = (const float*)d_in[12];
    const float* c_b   = (const float*)d_in[13];
    const float* in_proj_w = (const float*)d_in[14];
    const float* in_proj_b = (const float*)d_in[15];
    const float* out_w     = (const float*)d_in[16];
    const float* out_b     = (const float*)d_in[17];

    const int nv = in_sizes[3];
    const int N  = in_sizes[0] / (Rr * Hd);

    // workspace layout
    float* McT = (float*)d_ws;                         // 16384 f32
    float* bc  = McT + Hd * Hd;                        // 128 f32
    unsigned short* whi = (unsigned short*)(bc + Hd);  // 7*16384 u16
    unsigned short* wlo = whi + 7 * 16384;             // 7*16384 u16

    float* out_f    = (float*)d_out;
    float* out_tail = out_f + (size_t)nv * Hd;

    fold_proj_kernel<<<Hd, Hd, 0, stream>>>(in_proj_w, in_proj_b, out_w, out_b, McT, bc);
    pack_kernel<<<dim3(32, 7), 64, 0, stream>>>(r_whh, u_whh, r_wxh, u_wxh, c_whh, c_wxh,
                                                McT, whi, wlo);

    const int nodes_per_block = 4 * NPW;  // 128
    const int nblocks = (N + nodes_per_block - 1) / nodes_per_block;  // 235
    gru_mfma_kernel<<<nblocks, 256, 0, stream>>>(
        x_rank, valid_idx, nv, r_b, u_b, c_b, whi, wlo, bc, out_f, N);

    he_order_kernel<<<(nv + 255) / 256, 256, 0, stream>>>(he_order, out_tail, nv);
}